// Round 12
// baseline (179.024 us; speedup 1.0000x reference)
//
#include <hip/hip_runtime.h>
#include <math.h>

#define C_CH 256
#define T_LEN 4096

// R12: single fused launch. Drive blocks (0..2047) publish act/lat via
// RELAXED agent-scope atomic stores (sc1 write-through to the coherent LLC,
// bypassing gfx950's non-coherent per-XCD L2s -- NO buffer_wbl2 flush), wait
// vmcnt(0), then one RELAXED atomicAdd. Tail blocks (2048..2055, one per
// batch) prefetch MLP weights during drive, spin with RELAXED agent loads
// (no buffer_inv storm -- R4's mistake), then run R11's exact MLP.
// Counter zeroed by a 4-byte hipMemsetAsync node. Drive/MLP LDS overlaid in
// a union (37.5 KB) to keep 4 blocks/CU x 8 waves = 32 waves/CU for drive.

union SharedU {
    struct {
        float halo[2][8][512];      // double-buffered own-8 per region
        float wf[28];               // 27 folded taps + Beff
        float wavetot[8];
        float carry[8];
        int   smin[8];
    } d;
    struct {
        float act[256];
        union {
            float og[32][257];      // transpose tile (+1 pad)
            struct { float ph[4][128]; float pr[2][256]; } w;
        } u;
        float p[2][256];            // og partials
        float mixv[256];
        float hh[128];
    } m;
};

__global__ __launch_bounds__(512, 8) void fused_kernel(
    const float* __restrict__ x,
    const float* __restrict__ w3, const float* __restrict__ b3,
    const float* __restrict__ w5, const float* __restrict__ b5,
    const float* __restrict__ w9, const float* __restrict__ b9,
    const float* __restrict__ w_red, const float* __restrict__ b_red,
    const float* __restrict__ latency_scale,
    const float* __restrict__ og, const float* __restrict__ bias,
    const float* __restrict__ W1, const float* __restrict__ b1,
    const float* __restrict__ W2, const float* __restrict__ b2,
    float* __restrict__ sink, int* __restrict__ counter,
    float* __restrict__ out_pred, float* __restrict__ out_lat,
    float* __restrict__ out_act)
{
    const int blk = blockIdx.x;
    const int tid = threadIdx.x;
    __shared__ SharedU su;

    if (blk >= 2048) {
        // ==================== MLP tail block (one per batch) ================
        const int b = blk - 2048;
        const int t = tid;             // 0..511
        const int j = t & 255;
        const int g = t >> 8;

        // --- prefetch weights into L1/L2/LLC while drive runs ---
        {
            float acc = 0.0f;
            const int id = b * 512 + t;            // 0..4095
            const float4* og4 = (const float4*)og; // 16384 float4
            const float4* W14 = (const float4*)W1; // 8192
            const float4* W24 = (const float4*)W2; // 8192
            #pragma unroll
            for (int v = 0; v < 4; ++v) {
                float4 q = og4[id + v * 4096]; acc += q.x + q.y + q.z + q.w;
            }
            #pragma unroll
            for (int v = 0; v < 2; ++v) {
                float4 q = W14[id + v * 4096]; acc += q.x + q.y + q.z + q.w;
            }
            #pragma unroll
            for (int v = 0; v < 2; ++v) {
                float4 q = W24[id + v * 4096]; acc += q.x + q.y + q.z + q.w;
            }
            sink[id] = acc;                        // keep prefetch alive
        }

        // --- wait for all 2048 drive blocks (relaxed spin, no cache inv) ---
        if (t == 0) {
            while (__hip_atomic_load(counter, __ATOMIC_RELAXED,
                                     __HIP_MEMORY_SCOPE_AGENT) != 2048)
                __builtin_amdgcn_s_sleep(2);
        }
        __syncthreads();
        __atomic_signal_fence(__ATOMIC_SEQ_CST);

        // act: relaxed agent loads (sc1 -> read the LLC-coherent values)
        if (t < 256)
            su.m.act[t] = __hip_atomic_load(&out_act[b * 256 + t],
                                            __ATOMIC_RELAXED,
                                            __HIP_MEMORY_SCOPE_AGENT);

        // mixed[j] = bias[j] + sum_i act[i]*og[j,i]; 8 tiles of 32 i's,
        // group g accumulates tiles in its half (same association as R11).
        float mix = 0.0f;
        for (int m8 = 0; m8 < 8; ++m8) {
            const int i0 = m8 * 32;
            __syncthreads();           // also covers act staging (m8=0)
            #pragma unroll
            for (int q = 0; q < 16; ++q) {
                const int f  = (q << 9) + t;
                const int jj = f >> 5;
                const int ii = f & 31;
                su.m.u.og[ii][jj] = og[jj * 256 + i0 + ii];
            }
            __syncthreads();
            if ((m8 >> 2) == g) {
                #pragma unroll
                for (int ii = 0; ii < 32; ++ii)
                    mix = fmaf(su.m.act[i0 + ii], su.m.u.og[ii][j], mix);
            }
        }
        su.m.p[g][j] = mix;
        __syncthreads();
        if (t < 256) su.m.mixv[t] = bias[t] + su.m.p[0][t] + su.m.p[1][t];
        __syncthreads();

        // h[j1]: 4 partials per j1, fully-unrolled 64-load rounds (ph overlays
        // og -- last og read was two barriers ago).
        {
            const int j1  = t & 127;
            const int seg = t >> 7;
            float h = 0.0f;
            #pragma unroll
            for (int ii = 0; ii < 64; ++ii) {
                const int i = seg * 64 + ii;
                h = fmaf(su.m.mixv[i], W1[i * 128 + j1], h);
            }
            su.m.u.w.ph[seg][j1] = h;
        }
        __syncthreads();
        if (t < 128)
            su.m.hh[t] = fmaxf(b1[t] + ((su.m.u.w.ph[0][t] + su.m.u.w.ph[1][t])
                                      + (su.m.u.w.ph[2][t] + su.m.u.w.ph[3][t])), 0.0f);
        __syncthreads();

        // raw[j]: 2 partials per j, 64-load rounds.
        {
            float raw = 0.0f;
            #pragma unroll
            for (int kk = 0; kk < 64; ++kk) {
                const int k = g * 64 + kk;
                raw = fmaf(su.m.hh[k], W2[k * 256 + j], raw);
            }
            su.m.u.w.pr[g][j] = raw;
        }
        __syncthreads();
        if (t < 256) {
            const float r  = b2[t] + su.m.u.w.pr[0][t] + su.m.u.w.pr[1][t];
            const float sp = fmaxf(r, 0.0f) + log1pf(expf(-fabsf(r)));
            out_pred[b * 256 + t] = fminf(fmaxf(sp, 0.0f), 4096.0f);
        }
        return;
    }

    // ======================= drive + scan block ============================
    const int b    = blk >> 8;
    const int c    = blk & 255;
    const int lane = tid & 63;
    const int wv   = tid >> 6;                     // 0..7

    // --- parallel in-block weight fold (threads 0..27); covered by r=0 barrier
    if (tid < 27) {
        const int r = tid / 9, k = tid - 9 * r;
        const int q0     = 18 * c + 6 * r;
        const int region = (q0 >= 1536) + (q0 >= 3072);
        const int p0     = q0 - region * 1536;
        const int K      = (region == 0) ? 3 : (region == 1 ? 5 : 9);
        const int off    = (9 - K) >> 1;
        const float* wP  = (region == 0) ? w3 : (region == 1 ? w5 : w9);
        const int kk     = k - off;
        float w = 0.0f;
        if (kk >= 0 && kk < K) {
            const float* wr = w_red + c * 18 + 6 * r;
            #pragma unroll
            for (int j = 0; j < 6; ++j)
                w = fmaf(wr[j], wP[(p0 + j) * K + kk], w);
        }
        su.d.wf[tid] = w;
    } else if (tid == 27) {
        float acc = b_red[c];
        #pragma unroll
        for (int r = 0; r < 3; ++r) {
            const int q0     = 18 * c + 6 * r;
            const int region = (q0 >= 1536) + (q0 >= 3072);
            const int p0     = q0 - region * 1536;
            const float* bP  = (region == 0) ? b3 : (region == 1 ? b5 : b9);
            const float* wr  = w_red + c * 18 + 6 * r;
            #pragma unroll
            for (int j = 0; j < 6; ++j) acc = fmaf(wr[j], bP[p0 + j], acc);
        }
        su.d.wf[27] = acc;
    }

    // --- per-r: load own 8 floats, share via LDS, 9-tap FMA into d[8] ---
    const int t0 = tid << 3;                       // this thread's 8 steps
    float d[8];
    float Beff;
    #pragma unroll
    for (int r = 0; r < 3; ++r) {
        const int buf = r & 1;
        const int src = (3 * c + r) & 255;         // src row = (3c+r) mod 256
        const float4* p = (const float4*)(x + ((size_t)b * C_CH + src) * T_LEN + t0);
        float xa[16];                              // window [t0-4, t0+12)
        {
            float4 q0 = p[0], q1 = p[1];
            xa[4] = q0.x; xa[5] = q0.y; xa[6]  = q0.z; xa[7]  = q0.w;
            xa[8] = q1.x; xa[9] = q1.y; xa[10] = q1.z; xa[11] = q1.w;
        }
        #pragma unroll
        for (int e = 0; e < 8; ++e) su.d.halo[buf][e][tid] = xa[4 + e];
        __syncthreads();   // r=0: also publishes wf; dbuf kills WAR hazard
        if (r == 0) {
            Beff = su.d.wf[27];
            #pragma unroll
            for (int tt = 0; tt < 8; ++tt) d[tt] = Beff;
        }
        #pragma unroll
        for (int e = 0; e < 4; ++e)
            xa[e] = tid ? su.d.halo[buf][4 + e][tid - 1] : 0.0f;           // left
        #pragma unroll
        for (int e = 0; e < 4; ++e)
            xa[12 + e] = (tid < 511) ? su.d.halo[buf][e][tid + 1] : 0.0f;  // right
        #pragma unroll
        for (int k = 0; k < 9; ++k) {
            const float wk = su.d.wf[r * 9 + k];
            #pragma unroll
            for (int tt = 0; tt < 8; ++tt)
                d[tt] = fmaf(wk, xa[tt + k], d[tt]);
        }
    }

    const float A   = (float)0.8187307530779818;          // exp(-1/5), fp32
    const float OMA = (float)(1.0 - 0.8187307530779818);  // matches ref rounding

    // --- chunk-local scan: V after 8 steps from 0 ---
    float S = 0.0f;
    #pragma unroll
    for (int tt = 0; tt < 8; ++tt) S = A * S + OMA * d[tt];

    // --- wave-level weighted inclusive scan (per-chunk decay A^8) ---
    const float Fp[6] = {
        (float)2.0189651799465541e-01,  // A^8   = e^-1.6
        (float)4.0762203978366215e-02,  // A^16
        (float)1.6615572731739337e-03,  // A^32
        (float)2.7607725720371943e-06,  // A^64
        (float)7.6218649302532563e-12,  // A^128
        (float)5.8092835977683129e-23   // A^256
    };
    float cinc = S;
    #pragma unroll
    for (int s = 0; s < 6; ++s) {
        const int o = 1 << s;
        const float y = __shfl_up(cinc, o, 64);
        if (lane >= o) cinc = fmaf(Fp[s], y, cinc);
    }
    if (lane == 63) su.d.wavetot[wv] = cinc;
    __syncthreads();
    if (tid == 0) {
        // cross-wave decay A^512 ~ 3.4e-45 (denormal ~ 0)
        const float A512 = 3.3744728758705166e-45f;
        float g = 0.0f;
        #pragma unroll
        for (int w = 0; w < 8; ++w) { su.d.carry[w] = g; g = su.d.wavetot[w] + A512 * g; }
    }
    __syncthreads();
    const float cprev = __shfl_up(cinc, 1, 64);
    const float Vin = (lane ? cprev : 0.0f)
                    + expf(-1.6f * (float)lane) * su.d.carry[wv];

    // --- replay chunk with true incoming V; first threshold crossing ---
    float V = Vin;
    int firstT = T_LEN;
    #pragma unroll
    for (int tt = 0; tt < 8; ++tt) {
        V = A * V + OMA * d[tt];
        if (V >= 1.0f && firstT == T_LEN) firstT = t0 + tt;
    }

    // --- block min-reduce ---
    #pragma unroll
    for (int o = 32; o > 0; o >>= 1)
        firstT = min(firstT, __shfl_xor(firstT, o, 64));
    if (lane == 0) su.d.smin[wv] = firstT;
    __syncthreads();
    if (tid == 0) {
        int f = su.d.smin[0];
        #pragma unroll
        for (int w = 1; w < 8; ++w) f = min(f, su.d.smin[w]);
        const float lat   = (float)f;                          // T if never fired
        const float scale = fmaxf(latency_scale[0], 0.001f);
        // relaxed agent stores: sc1 write-through to LLC, no L2 flush
        __hip_atomic_store(&out_lat[blk], lat, __ATOMIC_RELAXED,
                           __HIP_MEMORY_SCOPE_AGENT);
        __hip_atomic_store(&out_act[blk], expf(-lat / scale), __ATOMIC_RELAXED,
                           __HIP_MEMORY_SCOPE_AGENT);
        __atomic_signal_fence(__ATOMIC_SEQ_CST);
        __builtin_amdgcn_s_waitcnt(0x0f70);   // vmcnt(0): stores retired @LLC
        __atomic_signal_fence(__ATOMIC_SEQ_CST);
        __hip_atomic_fetch_add(counter, 1, __ATOMIC_RELAXED,
                               __HIP_MEMORY_SCOPE_AGENT);
    }
}

// ---------------------------------------------------------------------------
extern "C" void kernel_launch(void* const* d_in, const int* in_sizes, int n_in,
                              void* d_out, int out_size, void* d_ws, size_t ws_size,
                              hipStream_t stream) {
    const float* x    = (const float*)d_in[0];
    const float* w3   = (const float*)d_in[1];
    const float* b3   = (const float*)d_in[2];
    const float* w5   = (const float*)d_in[3];
    const float* b5   = (const float*)d_in[4];
    const float* w9   = (const float*)d_in[5];
    const float* b9   = (const float*)d_in[6];
    const float* wred = (const float*)d_in[7];
    const float* bred = (const float*)d_in[8];
    const float* ls   = (const float*)d_in[9];
    const float* og   = (const float*)d_in[10];
    const float* bias = (const float*)d_in[11];
    const float* W1   = (const float*)d_in[12];
    const float* b1   = (const float*)d_in[13];
    const float* W2   = (const float*)d_in[14];
    const float* b2   = (const float*)d_in[15];

    int*   counter  = (int*)d_ws;             // [0]
    float* sink     = (float*)d_ws + 1024;    // 4 KB away from counter
    float* out      = (float*)d_out;
    float* out_pred = out;                    // (8,256)
    float* out_lat  = out + 2048;             // (8,256)
    float* out_act  = out + 4096;             // (8,256)

    hipMemsetAsync(counter, 0, 4, stream);    // zero completion counter
    fused_kernel<<<2056, 512, 0, stream>>>(
        x, w3, b3, w5, b5, w9, b9, wred, bred, ls,
        og, bias, W1, b1, W2, b2, sink, counter,
        out_pred, out_lat, out_act);
}

// Round 13
// 122.443 us; speedup vs baseline: 1.4621x; 1.4621x over previous
//
#include <hip/hip_runtime.h>
#include <math.h>

#define C_CH 256
#define T_LEN 4096

// R13 = R11 (best, 125.6us) + XCD-locality swizzle in drive.
// Fusion is dead: R3 (fences), R4 (acquire spin), R12 (relaxed atomics) all
// showed any intra-kernel cross-XCD producer->consumer costs 60-100us on
// gfx950. Kernel boundary is the only cheap sync.
// Swizzle: jj = ((i&7)<<5)|(i>>3) gives each XCD (round-robin dispatch) a
// contiguous jj-band; c = 171*jj mod 256 (171 = 3^-1 mod 256) makes block jj
// read source rows {jj, jj+1, jj+2} -> same-XCD L2 reuse of the 3x re-reads.

__global__ __launch_bounds__(512, 8) void drive_scan_kernel(
    const float* __restrict__ x,
    const float* __restrict__ w3, const float* __restrict__ b3,
    const float* __restrict__ w5, const float* __restrict__ b5,
    const float* __restrict__ w9, const float* __restrict__ b9,
    const float* __restrict__ w_red, const float* __restrict__ b_red,
    const float* __restrict__ latency_scale,
    const float* __restrict__ og, const float* __restrict__ W1,
    const float* __restrict__ W2, float* __restrict__ sink,
    float* __restrict__ out_lat, float* __restrict__ out_act)
{
    const int blk = blockIdx.x;
    const int tid = threadIdx.x;

    if (blk >= 2048) {
        // --- LLC prefetch of MLP weights, overlapped with drive ---
        const int id = (blk - 2048) * 512 + tid;   // 0..4095
        float acc = 0.0f;
        const float4* og4 = (const float4*)og;     // 16384 float4
        const float4* W14 = (const float4*)W1;     // 8192 float4
        const float4* W24 = (const float4*)W2;     // 8192 float4
        #pragma unroll
        for (int v = 0; v < 4; ++v) {
            float4 q = og4[id + v * 4096]; acc += q.x + q.y + q.z + q.w;
        }
        #pragma unroll
        for (int v = 0; v < 2; ++v) {
            float4 q = W14[id + v * 4096]; acc += q.x + q.y + q.z + q.w;
        }
        #pragma unroll
        for (int v = 0; v < 2; ++v) {
            float4 q = W24[id + v * 4096]; acc += q.x + q.y + q.z + q.w;
        }
        sink[id] = acc;                            // keep loads alive
        return;
    }

    const int b    = blk >> 8;
    const int i255 = blk & 255;
    // XCD-contiguous band index (dispatch round-robins blk % 8 across XCDs)
    const int jj   = ((i255 & 7) << 5) | (i255 >> 3);
    const int c    = (171 * jj) & 255;             // channel: 3*c = jj mod 256
    const int lane = tid & 63;
    const int wv   = tid >> 6;                     // 0..7

    __shared__ float sWF[28];                      // 27 folded taps + Beff
    __shared__ float sHalo[2][8][512];             // double-buffered own 8
    __shared__ float sWaveTot[8];
    __shared__ float sCarry[8];
    __shared__ int   sMin[8];

    // --- parallel in-block weight fold (threads 0..27); covered by r=0 barrier
    if (tid < 27) {
        const int r = tid / 9, k = tid - 9 * r;
        const int q0     = 18 * c + 6 * r;
        const int region = (q0 >= 1536) + (q0 >= 3072);
        const int p0     = q0 - region * 1536;
        const int K      = (region == 0) ? 3 : (region == 1 ? 5 : 9);
        const int off    = (9 - K) >> 1;
        const float* wP  = (region == 0) ? w3 : (region == 1 ? w5 : w9);
        const int kk     = k - off;
        float w = 0.0f;
        if (kk >= 0 && kk < K) {
            const float* wr = w_red + c * 18 + 6 * r;
            #pragma unroll
            for (int j = 0; j < 6; ++j)
                w = fmaf(wr[j], wP[(p0 + j) * K + kk], w);
        }
        sWF[tid] = w;
    } else if (tid == 27) {
        float acc = b_red[c];
        #pragma unroll
        for (int r = 0; r < 3; ++r) {
            const int q0     = 18 * c + 6 * r;
            const int region = (q0 >= 1536) + (q0 >= 3072);
            const int p0     = q0 - region * 1536;
            const float* bP  = (region == 0) ? b3 : (region == 1 ? b5 : b9);
            const float* wr  = w_red + c * 18 + 6 * r;
            #pragma unroll
            for (int j = 0; j < 6; ++j) acc = fmaf(wr[j], bP[p0 + j], acc);
        }
        sWF[27] = acc;
    }

    // --- per-r: load own 8 floats, share via LDS, 9-tap FMA into d[8] ---
    const int t0 = tid << 3;                       // this thread's 8 steps
    float d[8];
    float Beff;
    #pragma unroll
    for (int r = 0; r < 3; ++r) {
        const int buf = r & 1;
        const int src = (jj + r) & 255;            // rows jj, jj+1, jj+2
        const float4* p = (const float4*)(x + ((size_t)b * C_CH + src) * T_LEN + t0);
        float xa[16];                              // window [t0-4, t0+12)
        {
            float4 q0 = p[0], q1 = p[1];
            xa[4] = q0.x; xa[5] = q0.y; xa[6]  = q0.z; xa[7]  = q0.w;
            xa[8] = q1.x; xa[9] = q1.y; xa[10] = q1.z; xa[11] = q1.w;
        }
        #pragma unroll
        for (int e = 0; e < 8; ++e) sHalo[buf][e][tid] = xa[4 + e];
        __syncthreads();   // r=0: also publishes sWF; dbuf kills WAR hazard
        if (r == 0) {
            Beff = sWF[27];
            #pragma unroll
            for (int tt = 0; tt < 8; ++tt) d[tt] = Beff;
        }
        #pragma unroll
        for (int e = 0; e < 4; ++e)
            xa[e] = tid ? sHalo[buf][4 + e][tid - 1] : 0.0f;           // left
        #pragma unroll
        for (int e = 0; e < 4; ++e)
            xa[12 + e] = (tid < 511) ? sHalo[buf][e][tid + 1] : 0.0f;  // right
        #pragma unroll
        for (int k = 0; k < 9; ++k) {
            const float wk = sWF[r * 9 + k];
            #pragma unroll
            for (int tt = 0; tt < 8; ++tt)
                d[tt] = fmaf(wk, xa[tt + k], d[tt]);
        }
    }

    const float A   = (float)0.8187307530779818;          // exp(-1/5), fp32
    const float OMA = (float)(1.0 - 0.8187307530779818);  // matches ref rounding

    // --- chunk-local scan: V after 8 steps from 0 ---
    float S = 0.0f;
    #pragma unroll
    for (int tt = 0; tt < 8; ++tt) S = A * S + OMA * d[tt];

    // --- wave-level weighted inclusive scan (per-chunk decay A^8) ---
    const float Fp[6] = {
        (float)2.0189651799465541e-01,  // A^8   = e^-1.6
        (float)4.0762203978366215e-02,  // A^16
        (float)1.6615572731739337e-03,  // A^32
        (float)2.7607725720371943e-06,  // A^64
        (float)7.6218649302532563e-12,  // A^128
        (float)5.8092835977683129e-23   // A^256
    };
    float cinc = S;
    #pragma unroll
    for (int s = 0; s < 6; ++s) {
        const int o = 1 << s;
        const float y = __shfl_up(cinc, o, 64);
        if (lane >= o) cinc = fmaf(Fp[s], y, cinc);
    }
    if (lane == 63) sWaveTot[wv] = cinc;
    __syncthreads();
    if (tid == 0) {
        // cross-wave decay A^512 ~ 3.4e-45 (denormal ~ 0)
        const float A512 = 3.3744728758705166e-45f;
        float g = 0.0f;
        #pragma unroll
        for (int w = 0; w < 8; ++w) { sCarry[w] = g; g = sWaveTot[w] + A512 * g; }
    }
    __syncthreads();
    const float cprev = __shfl_up(cinc, 1, 64);
    const float Vin = (lane ? cprev : 0.0f)
                    + expf(-1.6f * (float)lane) * sCarry[wv];

    // --- replay chunk with true incoming V; first threshold crossing ---
    float V = Vin;
    int firstT = T_LEN;
    #pragma unroll
    for (int tt = 0; tt < 8; ++tt) {
        V = A * V + OMA * d[tt];
        if (V >= 1.0f && firstT == T_LEN) firstT = t0 + tt;
    }

    // --- block min-reduce ---
    #pragma unroll
    for (int o = 32; o > 0; o >>= 1)
        firstT = min(firstT, __shfl_xor(firstT, o, 64));
    if (lane == 0) sMin[wv] = firstT;
    __syncthreads();
    if (tid == 0) {
        int f = sMin[0];
        #pragma unroll
        for (int w = 1; w < 8; ++w) f = min(f, sMin[w]);
        const float lat   = (float)f;                          // T if never fired
        const float scale = fmaxf(latency_scale[0], 0.001f);
        out_lat[(b << 8) + c] = lat;
        out_act[(b << 8) + c] = expf(-lat / scale);
    }
}

// ---------------------------------------------------------------------------
// K2: gated mix + 2-layer MLP + softplus/clip. One 512-thread block per
// batch row; split reductions collapse dependent-load chains to 1-2 latency
// rounds. Weights LLC-warm from drive-phase prefetch blocks.
// ---------------------------------------------------------------------------
__global__ __launch_bounds__(512) void mlp_kernel(
    const float* __restrict__ act,
    const float* __restrict__ og, const float* __restrict__ bias,
    const float* __restrict__ W1, const float* __restrict__ b1,
    const float* __restrict__ W2, const float* __restrict__ b2,
    float* __restrict__ out_pred)
{
    const int b = blockIdx.x;
    const int t = threadIdx.x;
    const int j = t & 255;             // output index for og/W2 phases
    const int g = t >> 8;              // reduction group 0/1

    __shared__ float sAct[256];
    __shared__ float sOg[2][32][257];  // per-group transpose tile (+1 pad)
    __shared__ float sP[2][256];       // og partials
    __shared__ float sMix[256];
    __shared__ float sPH[4][128];      // W1 partials
    __shared__ float sH[128];
    __shared__ float sPR[2][256];      // W2 partials

    if (t < 256) sAct[t] = act[b * 256 + t];

    // mixed[j] = bias[j] + sum_i act[i]*og[j,i]; group g covers i in
    // [g*128, g*128+128) via 4 LDS transpose tiles of 32 i's.
    float mix = 0.0f;
    for (int m = 0; m < 4; ++m) {
        const int i0 = g * 128 + m * 32;
        __syncthreads();               // protect previous tile's readers
        #pragma unroll
        for (int q = 0; q < 32; ++q) {
            const int f  = (q << 8) + j;
            const int jjj = f >> 5;
            const int ii  = f & 31;
            sOg[g][ii][jjj] = og[jjj * 256 + i0 + ii];
        }
        __syncthreads();
        #pragma unroll
        for (int ii = 0; ii < 32; ++ii)
            mix = fmaf(sAct[i0 + ii], sOg[g][ii][j], mix);
    }
    sP[g][j] = mix;
    __syncthreads();
    if (t < 256) sMix[t] = bias[t] + sP[0][t] + sP[1][t];
    __syncthreads();

    // h[j1] = relu(b1 + sum_i mixed[i]*W1[i,j1]); 4 partials per j1, each a
    // fully-unrolled 64-load round. W1 (256,128) row-major: coalesced.
    {
        const int j1  = t & 127;
        const int seg = t >> 7;        // 0..3
        float h = 0.0f;
        #pragma unroll
        for (int ii = 0; ii < 64; ++ii) {
            const int i = seg * 64 + ii;
            h = fmaf(sMix[i], W1[i * 128 + j1], h);
        }
        sPH[seg][j1] = h;
    }
    __syncthreads();
    if (t < 128)
        sH[t] = fmaxf(b1[t] + ((sPH[0][t] + sPH[1][t]) + (sPH[2][t] + sPH[3][t])), 0.0f);
    __syncthreads();

    // raw[j] = b2[j] + sum_k h[k]*W2[k,j]; 2 partials per j, 64-load rounds.
    {
        float raw = 0.0f;
        #pragma unroll
        for (int kk = 0; kk < 64; ++kk) {
            const int k = g * 64 + kk;
            raw = fmaf(sH[k], W2[k * 256 + j], raw);
        }
        sPR[g][j] = raw;
    }
    __syncthreads();
    if (t < 256) {
        const float r  = b2[t] + sPR[0][t] + sPR[1][t];
        const float sp = fmaxf(r, 0.0f) + log1pf(expf(-fabsf(r)));
        out_pred[b * 256 + t] = fminf(fmaxf(sp, 0.0f), 4096.0f);
    }
}

// ---------------------------------------------------------------------------
extern "C" void kernel_launch(void* const* d_in, const int* in_sizes, int n_in,
                              void* d_out, int out_size, void* d_ws, size_t ws_size,
                              hipStream_t stream) {
    const float* x    = (const float*)d_in[0];
    const float* w3   = (const float*)d_in[1];
    const float* b3   = (const float*)d_in[2];
    const float* w5   = (const float*)d_in[3];
    const float* b5   = (const float*)d_in[4];
    const float* w9   = (const float*)d_in[5];
    const float* b9   = (const float*)d_in[6];
    const float* wred = (const float*)d_in[7];
    const float* bred = (const float*)d_in[8];
    const float* ls   = (const float*)d_in[9];
    const float* og   = (const float*)d_in[10];
    const float* bias = (const float*)d_in[11];
    const float* W1   = (const float*)d_in[12];
    const float* b1   = (const float*)d_in[13];
    const float* W2   = (const float*)d_in[14];
    const float* b2   = (const float*)d_in[15];

    float* sink     = (float*)d_ws;     // prefetch sink (4096 floats)
    float* out      = (float*)d_out;
    float* out_pred = out;              // (8,256)
    float* out_lat  = out + 2048;       // (8,256)
    float* out_act  = out + 4096;       // (8,256)

    drive_scan_kernel<<<2056, 512, 0, stream>>>(
        x, w3, b3, w5, b5, w9, b9, wred, bred, ls,
        og, W1, W2, sink, out_lat, out_act);
    mlp_kernel<<<8, 512, 0, stream>>>(out_act, og, bias, W1, b1, W2, b2, out_pred);
}